// Round 2
// baseline (78880.737 us; speedup 1.0000x reference)
//
#include <hip/hip_runtime.h>
#include <cstdint>
#include <math.h>

typedef unsigned int u32;

#define BB 256   // batch
#define NN 256   // nodes
#define EE 256   // enc dim
#define HH 512   // hidden
#define G4 2048  // 4H
#define KK 768   // E + H
#define TT 256   // steps

// ---------------- Threefry-2x32, exactly as jax/_src/prng.py ----------------
__device__ __forceinline__ u32 rotl(u32 x, int d) { return (x << d) | (x >> (32 - d)); }

__device__ __forceinline__ void tf4(u32& x0, u32& x1, int r0, int r1, int r2, int r3) {
  x0 += x1; x1 = rotl(x1, r0); x1 ^= x0;
  x0 += x1; x1 = rotl(x1, r1); x1 ^= x0;
  x0 += x1; x1 = rotl(x1, r2); x1 ^= x0;
  x0 += x1; x1 = rotl(x1, r3); x1 ^= x0;
}

__device__ __forceinline__ void threefry2x32(u32 k0, u32 k1, u32 x0, u32 x1, u32& o0, u32& o1) {
  u32 k2 = k0 ^ k1 ^ 0x1BD11BDAu;
  x0 += k0; x1 += k1;
  tf4(x0, x1, 13, 15, 26, 6);  x0 += k1; x1 += k2 + 1u;
  tf4(x0, x1, 17, 29, 16, 24); x0 += k2; x1 += k0 + 2u;
  tf4(x0, x1, 13, 15, 26, 6);  x0 += k0; x1 += k1 + 3u;
  tf4(x0, x1, 17, 29, 16, 24); x0 += k1; x1 += k2 + 4u;
  tf4(x0, x1, 13, 15, 26, 6);  x0 += k2; x1 += k0 + 5u;
  o0 = x0; o1 = x1;
}

// jax_threefry_partitionable=True (modern default):
// split(key(42), 256): counts = 64-bit iota over shape (256,) as (hi, lo) u32 pairs;
// key_t = threefry((0,42), hi=0, lo=t) -> (o0, o1) stacked on last axis.
__global__ void keys_kernel(u32* __restrict__ keys) {
  int t = threadIdx.x;  // 0..255
  u32 o0, o1;
  threefry2x32(0u, 42u, 0u, (u32)t, o0, o1);
  keys[2 * t] = o0; keys[2 * t + 1] = o1;
}

// ---------------- setup: transposed weights, fused bias --------------------
__global__ void build_kernel(const float* __restrict__ W_ih, const float* __restrict__ W_hh,
                             const float* __restrict__ b_ih, const float* __restrict__ b_hh,
                             const float* __restrict__ W_q,
                             float* __restrict__ Wc, float* __restrict__ WqT,
                             double* __restrict__ bsum) {
  int idx = blockIdx.x * 256 + threadIdx.x;
  if (idx < KK * G4) {
    int k = idx >> 11, j = idx & 2047;
    Wc[idx] = (k < EE) ? W_ih[j * EE + k] : W_hh[j * HH + (k - EE)];
  }
  if (idx < HH * HH) {
    int h2 = idx >> 9, h = idx & 511;
    WqT[idx] = W_q[h * HH + h2];
  }
  if (idx < G4) bsum[idx] = (double)b_ih[idx] + (double)b_hh[idx];
}

// ---------------- k_encT[b][h][n] = sum_e enc[b][n][e] * W_k[h][e] ----------
// block: 256 thr, tile 64h x 64n per b; fp64 accumulate, fp32 store.
__global__ __launch_bounds__(256) void kenc_kernel(const float* __restrict__ enc,
                                                   const float* __restrict__ Wk,
                                                   float* __restrict__ kT) {
  __shared__ float encS[64][65];
  __shared__ float wkS[64][65];
  const int b = blockIdx.z, h0 = blockIdx.x * 64, n0 = blockIdx.y * 64;
  const int t = threadIdx.x;
  const int tn = t & 63, th = t >> 6;  // th in 0..3
  double acc[16];
#pragma unroll
  for (int i = 0; i < 16; i++) acc[i] = 0.0;
  for (int ec = 0; ec < EE; ec += 64) {
#pragma unroll
    for (int i = 0; i < 16; i++) {
      int idx = i * 256 + t;
      int r = idx >> 6, cc = idx & 63;
      encS[r][cc] = enc[((size_t)b * NN + (n0 + r)) * EE + ec + cc];
      wkS[r][cc]  = Wk[(size_t)(h0 + r) * EE + ec + cc];
    }
    __syncthreads();
#pragma unroll 8
    for (int e = 0; e < 64; e++) {
      double ev = (double)encS[tn][e];
#pragma unroll
      for (int i = 0; i < 16; i++) acc[i] += (double)wkS[th * 16 + i][e] * ev;
    }
    __syncthreads();
  }
#pragma unroll
  for (int i = 0; i < 16; i++)
    kT[((size_t)b * HH + h0 + th * 16 + i) * NN + n0 + tn] = (float)acc[i];
}

// ---------------- generic small fp64 GEMM: C[b][j] = A[b][:klen] @ Bf + bias -
// tile 32 rows x 64 cols, 256 threads, each thread 2x4 outputs.
__global__ __launch_bounds__(256) void gemm_kernel(const double* __restrict__ A, int lda, int klen,
                                                   const float* __restrict__ Bf, int ldb,
                                                   const double* __restrict__ bias,
                                                   double* __restrict__ C, int ldc) {
  __shared__ double aS[32][33];
  __shared__ float  bS[32][65];
  const int jt = blockIdx.x * 64, bt = blockIdx.y * 32;
  const int t = threadIdx.x;
  const int tx = t & 15, ty = t >> 4;
  double acc[2][4];
#pragma unroll
  for (int i = 0; i < 2; i++)
#pragma unroll
    for (int j = 0; j < 4; j++) acc[i][j] = bias ? bias[jt + tx * 4 + j] : 0.0;
  for (int kc = 0; kc < klen; kc += 32) {
#pragma unroll
    for (int i = 0; i < 4; i++) {
      int idx = i * 256 + t; int r = idx >> 5, c = idx & 31;
      aS[r][c] = A[(size_t)(bt + r) * lda + kc + c];
    }
#pragma unroll
    for (int i = 0; i < 8; i++) {
      int idx = i * 256 + t; int r = idx >> 6, c = idx & 63;
      bS[r][c] = Bf[(size_t)(kc + r) * ldb + jt + c];
    }
    __syncthreads();
#pragma unroll 8
    for (int kk = 0; kk < 32; kk++) {
      double a0 = aS[ty * 2][kk], a1 = aS[ty * 2 + 1][kk];
#pragma unroll
      for (int j = 0; j < 4; j++) {
        double bv = (double)bS[kk][tx * 4 + j];
        acc[0][j] += a0 * bv;
        acc[1][j] += a1 * bv;
      }
    }
    __syncthreads();
  }
#pragma unroll
  for (int i = 0; i < 2; i++)
#pragma unroll
    for (int j = 0; j < 4; j++)
      C[(size_t)(bt + ty * 2 + i) * ldc + jt + tx * 4 + j] = acc[i][j];
}

// ---------------- LSTM elementwise --------------------------------------
__global__ void lstm_kernel(const double* __restrict__ gates, double* __restrict__ c,
                            double* __restrict__ x) {
  int idx = blockIdx.x * 256 + threadIdx.x;  // 131072
  int b = idx >> 9, jj = idx & 511;
  const double* g = gates + (size_t)b * G4;
  double ig = g[jj], fg = g[512 + jj], gg = g[1024 + jj], og = g[1536 + jj];
  double si = 1.0 / (1.0 + exp(-ig));
  double sf = 1.0 / (1.0 + exp(-fg));
  double so = 1.0 / (1.0 + exp(-og));
  double cn = sf * c[idx] + si * tanh(gg);
  c[idx] = cn;
  x[(size_t)b * KK + EE + jj] = so * tanh(cn);
}

// ---------------- attention + gumbel argmax + softmax + state update ------
__global__ __launch_bounds__(512) void attn_sample_kernel(
    const float* __restrict__ kT, const double* __restrict__ q,
    const float* __restrict__ v, const float* __restrict__ enc,
    double* __restrict__ x, int* __restrict__ visited, double* __restrict__ logp,
    const u32* __restrict__ keys, int step, float* __restrict__ out) {
  __shared__ double qS[HH];
  __shared__ float vS[HH];
  __shared__ double red[512];
  __shared__ double sS[256];
  __shared__ int redi[256];
  __shared__ int idxS;
  const int b = blockIdx.x;
  const int t = threadIdx.x;           // 512 threads
  const int n = t & 255, half = t >> 8;
  qS[t] = q[(size_t)b * HH + t];
  vS[t] = v[t];
  __syncthreads();

  // partial score over one half of h (256 elems), coalesced over n
  const float* kp = kT + ((size_t)b * HH + half * 256) * NN + n;
  double a0 = 0.0, a1 = 0.0;
#pragma unroll 4
  for (int h = 0; h < 256; h += 2) {
    float k0 = kp[(size_t)h * NN];
    float k1 = kp[(size_t)(h + 1) * NN];
    int hh = half * 256 + h;
    a0 += (double)vS[hh]     * (double)tanhf((float)(qS[hh]     + (double)k0));
    a1 += (double)vS[hh + 1] * (double)tanhf((float)(qS[hh + 1] + (double)k1));
  }
  red[t] = a0 + a1;
  __syncthreads();

  if (t < 256) {
    double s = red[t] + red[256 + t];
    if (visited[b * 256 + t]) s -= 1.0e6;
    sS[t] = s;
  }
  __syncthreads();

  // gumbel noise: jax_threefry_partitionable=True categorical.
  // random_bits(key_t, 32, (256,256)): element (b,n) has 64-bit counter
  // flat = b*256+n -> (o0,o1) = threefry(key_t, 0, flat); bits = o0 ^ o1.
  if (t < 256) {
    u32 fl = (u32)(b * 256 + t);
    u32 o0, o1;
    threefry2x32(keys[2 * step], keys[2 * step + 1], 0u, fl, o0, o1);
    u32 bits = o0 ^ o1;
    u32 fb = (bits >> 9) | 0x3F800000u;
    float uf = __uint_as_float(fb) - 1.0f;
    double u = (uf > 0.0f) ? (double)uf : (double)1.17549435e-38f;
    double gmb = -log(-log(u));
    red[t] = gmb + sS[t];
    redi[t] = t;
  }
  __syncthreads();
  // argmax, first-index on ties
  for (int s2 = 128; s2 > 0; s2 >>= 1) {
    if (t < s2) {
      double v1 = red[t], v2 = red[t + s2];
      int i1 = redi[t], i2 = redi[t + s2];
      if (v2 > v1 || (v2 == v1 && i2 < i1)) { red[t] = v2; redi[t] = i2; }
    }
    __syncthreads();
  }
  if (t == 0) idxS = redi[0];

  // softmax max
  if (t < 256) red[t] = sS[t];
  __syncthreads();
  for (int s2 = 128; s2 > 0; s2 >>= 1) {
    if (t < s2) red[t] = fmax(red[t], red[t + s2]);
    __syncthreads();
  }
  double m = red[0];
  __syncthreads();
  if (t < 256) red[t] = exp(sS[t] - m);
  __syncthreads();
  for (int s2 = 128; s2 > 0; s2 >>= 1) {
    if (t < s2) red[t] += red[t + s2];
    __syncthreads();
  }
  if (t == 0) {
    int bi = idxS;
    double p = exp(sS[bi] - m) / red[0];
    logp[b] += p;
    out[(size_t)b * TT + step] = (float)bi;
    visited[b * 256 + bi] = 1;
  }
  __syncthreads();
  if (t < 256) x[(size_t)b * KK + t] = (double)enc[((size_t)b * NN + idxS) * EE + t];
}

__global__ void finalize_kernel(const double* __restrict__ logp, float* __restrict__ out) {
  int b = threadIdx.x;
  out[BB * TT + b] = (float)logp[b];
}

// ---------------- host launch ---------------------------------------------
extern "C" void kernel_launch(void* const* d_in, const int* in_sizes, int n_in,
                              void* d_out, int out_size, void* d_ws, size_t ws_size,
                              hipStream_t stream) {
  const float* enc  = (const float*)d_in[0];
  const float* W_ih = (const float*)d_in[1];
  const float* W_hh = (const float*)d_in[2];
  const float* b_ih = (const float*)d_in[3];
  const float* b_hh = (const float*)d_in[4];
  const float* W_q  = (const float*)d_in[5];
  const float* W_k  = (const float*)d_in[6];
  const float* v    = (const float*)d_in[7];
  float* out = (float*)d_out;

  char* ws = (char*)d_ws;
  // offsets (bytes)
  float*  kT      = (float*)(ws + 0);                         // 256*512*256*4 = 134217728
  float*  Wc      = (float*)(ws + 134217728);                 // 768*2048*4    =   6291456
  float*  WqT     = (float*)(ws + 140509184);                 // 512*512*4     =   1048576
  double* bsum    = (double*)(ws + 141557760);                // 2048*8        =     16384
  u32*    keys    = (u32*)(ws + 141574144);                   // 512*4         =      2048
  double* gates   = (double*)(ws + 141576192);                // 256*2048*8    =   4194304
  double* q       = (double*)(ws + 145770496);                // 256*512*8     =   1048576
  double* x       = (double*)(ws + 146819072);                // 256*768*8     =   1572864
  double* c       = (double*)(ws + 148391936);                // 256*512*8     =   1048576
  int*    visited = (int*)(ws + 149440512);                   // 256*256*4     =    262144
  double* logp    = (double*)(ws + 149702656);                // 256*8         =      2048

  // zero state: x, c, visited, logp are contiguous
  hipMemsetAsync((void*)x, 0, 149704704 - 146819072, stream);

  keys_kernel<<<1, 256, 0, stream>>>(keys);
  build_kernel<<<(KK * G4 + 255) / 256, 256, 0, stream>>>(W_ih, W_hh, b_ih, b_hh, W_q, Wc, WqT, bsum);
  kenc_kernel<<<dim3(8, 4, 256), 256, 0, stream>>>(enc, W_k, kT);

  for (int t = 0; t < TT; t++) {
    // gates = [start; h] @ Wc + (b_ih + b_hh)
    gemm_kernel<<<dim3(32, 8), 256, 0, stream>>>(x, KK, KK, Wc, G4, bsum, gates, G4);
    lstm_kernel<<<512, 256, 0, stream>>>(gates, c, x);
    // q = h @ W_q^T
    gemm_kernel<<<dim3(8, 8), 256, 0, stream>>>(x + EE, KK, HH, WqT, HH, nullptr, q, HH);
    attn_sample_kernel<<<256, 512, 0, stream>>>(kT, q, v, enc, x, visited, logp, keys, t, out);
  }
  finalize_kernel<<<1, 256, 0, stream>>>(logp, out);
}